// Round 11
// baseline (1472.992 us; speedup 1.0000x reference)
//
#include <hip/hip_runtime.h>
#include <math.h>

// Problem constants
#define Bn 256
#define Tn 100
#define In 1024
#define Hn 2048
#define On 10
#define Kc (In + Hn)   // 3072 concatenated K

typedef short s8v  __attribute__((ext_vector_type(8)));   // 8 x bf16 (as raw shorts), 4 VGPRs
typedef unsigned short us4 __attribute__((ext_vector_type(4)));
typedef float f32x4 __attribute__((ext_vector_type(4)));

__device__ __forceinline__ unsigned short f2bf(float f) {
    unsigned int u = __float_as_uint(f);
    u += 0x7fffu + ((u >> 16) & 1u);   // round-to-nearest-even
    return (unsigned short)(u >> 16);
}

// Branch-free exact tanh: 1 - 2/(exp(2x)+1). ~1e-6 abs err, under bf16 rounding.
__device__ __forceinline__ float fast_tanh(float x) {
    float e = __expf(x + x);
    return 1.0f - 2.0f * __builtin_amdgcn_rcpf(e + 1.0f);
}

// ---- setup kernels -------------------------------------------------------

// x [B][T][I] fp32 -> bf16, 4 elems/thread
__global__ void conv_x_kernel(const float4* __restrict__ src, ushort4* __restrict__ dst) {
    int i = blockIdx.x * 256 + threadIdx.x;
    float4 v = src[i];
    ushort4 o;
    o.x = f2bf(v.x); o.y = f2bf(v.y); o.z = f2bf(v.z); o.w = f2bf(v.w);
    dst[i] = o;
}

// src [K][N=2048] fp32 -> dst[n][colOff + k] bf16  (builds B^T = [Win;W]^T rows)
__global__ void transpose_bf16_kernel(const float* __restrict__ src, unsigned short* __restrict__ dst,
                                      int N, int ld, int colOff) {
    __shared__ float tile[32][33];
    int k0 = blockIdx.x * 32;
    int n0 = blockIdx.y * 32;
    int c = threadIdx.x & 31;
    int r = threadIdx.x >> 5;            // 0..7
    #pragma unroll
    for (int i = 0; i < 32; i += 8)
        tile[r + i][c] = src[(size_t)(k0 + r + i) * N + n0 + c];
    __syncthreads();
    #pragma unroll
    for (int i = 0; i < 32; i += 8)
        dst[(size_t)(n0 + r + i) * ld + colOff + k0 + c] = f2bf(tile[c][r + i]);
}

// h0 -> h_all slot 0 (bf16); lin_w -> padded bf16 [16][2048]; zero barrier block
__global__ void small_conv_kernel(const float* __restrict__ h0, const float* __restrict__ lin_w,
                                  unsigned short* __restrict__ h_all0, unsigned short* __restrict__ lwb,
                                  unsigned int* __restrict__ bar) {
    int idx = blockIdx.x * 256 + threadIdx.x;
    if (idx < 512) bar[idx] = 0u;        // per-tile flags (8 chains x 64), re-zeroed every launch
    if (idx < Bn * Hn) {
        h_all0[idx] = f2bf(h0[idx]);
    } else {
        int j = idx - Bn * Hn;           // < 16*2048 exactly (grid sized for it)
        int o = j >> 11;
        int k = j & 2047;
        lwb[j] = (o < On) ? f2bf(lin_w[o * Hn + k]) : (unsigned short)0;
    }
}

// ---- scan helpers --------------------------------------------------------

// h-part: 8 chunks (rotated), depth-2 ring, 2 m-frags x 2 n-frags
__device__ __forceinline__ void hpart(f32x4 (&acc)[2][2], const s8v (&bh)[8][2],
                                      const unsigned short* hrow, int hoff) {
    s8v A2[2][2];
    #pragma unroll
    for (int r = 0; r < 2; ++r)
        A2[0][r] = *(const s8v*)(hrow + hoff * 32 + r * 16 * Hn);
    #pragma unroll
    for (int c = 0; c < 8; ++c) {
        if (c < 7) {
            const unsigned short* p = hrow + ((c + 1 + hoff) & 7) * 32;
            #pragma unroll
            for (int r = 0; r < 2; ++r)
                A2[(c + 1) & 1][r] = *(const s8v*)(p + r * 16 * Hn);
        }
        const s8v a0 = A2[c & 1][0];
        const s8v a1 = A2[c & 1][1];
        acc[0][0] = __builtin_amdgcn_mfma_f32_16x16x32_bf16(a0, bh[c][0], acc[0][0], 0, 0, 0);
        acc[1][0] = __builtin_amdgcn_mfma_f32_16x16x32_bf16(a1, bh[c][0], acc[1][0], 0, 0, 0);
        acc[0][1] = __builtin_amdgcn_mfma_f32_16x16x32_bf16(a0, bh[c][1], acc[0][1], 0, 0, 0);
        acc[1][1] = __builtin_amdgcn_mfma_f32_16x16x32_bf16(a1, bh[c][1], acc[1][1], 0, 0, 0);
    }
}

// x-part: 4 chunks (rotated), all loads upfront
__device__ __forceinline__ void xpart(f32x4 (&acc)[2][2], const s8v (&bx)[4][2],
                                      const unsigned short* ar, int xoff, size_t xrow) {
    s8v X[4][2];
    #pragma unroll
    for (int c = 0; c < 4; ++c)
        #pragma unroll
        for (int r = 0; r < 2; ++r)
            X[c][r] = *(const s8v*)(ar + ((c + xoff) & 3) * 32 + r * 16 * xrow);
    #pragma unroll
    for (int c = 0; c < 4; ++c) {
        acc[0][0] = __builtin_amdgcn_mfma_f32_16x16x32_bf16(X[c][0], bx[c][0], acc[0][0], 0, 0, 0);
        acc[1][0] = __builtin_amdgcn_mfma_f32_16x16x32_bf16(X[c][1], bx[c][0], acc[1][0], 0, 0, 0);
        acc[0][1] = __builtin_amdgcn_mfma_f32_16x16x32_bf16(X[c][0], bx[c][1], acc[0][1], 0, 0, 0);
        acc[1][1] = __builtin_amdgcn_mfma_f32_16x16x32_bf16(X[c][1], bx[c][1], acc[1][1], 0, 0, 0);
    }
}

__device__ __forceinline__ void zero_acc(f32x4 (&acc)[2][2]) {
    #pragma unroll
    for (int mi = 0; mi < 2; ++mi)
        #pragma unroll
        for (int ni = 0; ni < 2; ++ni)
            acc[mi][ni] = (f32x4){0.f, 0.f, 0.f, 0.f};
}

// ---- persistent scan -----------------------------------------------------
// R15 = DUAL-CHAIN ANTI-PHASE. R14 post-mortem: correct per-wave poll ~= R10
// (1163 vs 1174) -> the per-step tail is COMMON-MODE latency (store-drain ack
// + flag L3 visibility + poll RTT + first-load RTT, ~2.5-4us) that no
// single-chain scheduling can hide. The batch rows ARE independent chains:
// 8 chains of 32 rows; block b serves chain b&3 (A-half) and chain 4+(b&3)
// (B-half) at the same n-tile nIdx=b>>2 (64 n-tiles of 32/chain).
//  * ANTI-PHASE HIDING: flagA is published mid-iteration and polled at the
//    NEXT iteration start -> slack = the whole B-half (~half step). flagB:
//    published at iteration end, polled mid-iteration -> slack = A-half.
//    All common-mode RTTs now complete off-chain.
//  * SHARED B-FRAGS: both tiles use the same n-columns -> one bx/bh copy.
//    Persistent regs = bh 64 + bx 32 + accA 16 + accB 16 = 128 (== R10).
//    A-ring halves (2 m-frags). No R8/R11-style regalloc blow-up.
//  * L2 traffic drops ~33%: h slab/chain = 128KB read by 64 tiles (was
//    256KB x 64).
//  * Arithmetic is BIT-IDENTICAL per output elem (same k-order per wave,
//    same 8-slab pairwise tree, same per-nIdx rotation) -> absmax must be
//    exactly 0.015625.
// Per-chain sync protocol is R14's proven one, verbatim: relaxed agent-scope
// write-through h stores; __syncthreads (vmcnt(0)) drains the store before
// the nIdx-DIRECT flag; per-wave poll of the 8 producer flags
// [w*8, w*8+8); memory clobber after poll; fresh h addresses each step.
__global__ __launch_bounds__(512, 2)
void scan_kernel(const unsigned short* __restrict__ xb,
                 const unsigned short* __restrict__ BTm,
                 unsigned short* __restrict__ h_all,
                 unsigned int* __restrict__ bar) {
    const int g = blockIdx.x;
    const int cA = g & 3;                               // chain A: rows [cA*32,+32)
    const int m0A = cA * 32;
    const int m0B = 128 + m0A;                          // chain B = cA+4
    const int nIdx = g >> 2;                            // 0..63
    const int n0 = nIdx * 32;
    const int w = threadIdx.x >> 6;                     // 0..7
    const int lane = threadIdx.x & 63;
    const int quad = lane >> 4;
    const int lr = lane & 15;
    const int hoff = nIdx & 7;                          // h k-rotation (anti-convoy)
    const int xoff = nIdx & 3;                          // x k-rotation

    __shared__ float redA[8][32][36];                   // pad 36: 2-way banks (free)
    __shared__ float redB[8][32][36];

    const unsigned short* bp0 = BTm + (size_t)(n0 + lr) * Kc;
    const unsigned short* bp1 = BTm + (size_t)(n0 + 16 + lr) * Kc;

    const size_t xrow = (size_t)Tn * In;                // x row stride (102400)

    // flags: bar[chain*64 + nIdx], nIdx-DIRECT (R14 lesson)
    unsigned int* flA = bar + cA * 64;
    unsigned int* flB = bar + (4 + cA) * 64;
    const int fA = cA * 64 + nIdx;
    const int fB = (4 + cA) * 64 + nIdx;

    // ---- one-time B-fragment preload, PRE-ROTATED (shared by both chains) ----
    s8v bx[4][2];                                       // bx[c] = x-chunk (c+xoff)&3
    s8v bh[8][2];                                       // bh[c] = h-chunk (c+hoff)&7
    #pragma unroll
    for (int c = 0; c < 4; ++c) {
        const int kq = w * 128 + (((c + xoff) & 3) * 32) + quad * 8;
        bx[c][0] = *(const s8v*)(bp0 + kq);
        bx[c][1] = *(const s8v*)(bp1 + kq);
    }
    #pragma unroll
    for (int c = 0; c < 8; ++c) {
        const int kq = In + w * 256 + (((c + hoff) & 7) * 32) + quad * 8;
        bh[c][0] = *(const s8v*)(bp0 + kq);
        bh[c][1] = *(const s8v*)(bp1 + kq);
    }

    f32x4 accA[2][2], accB[2][2];
    zero_acc(accA);
    zero_acc(accB);

    // ---- x-parts for t=0, both chains ----
    xpart(accA, bx, xb + (size_t)(m0A + lr) * xrow + w * 128 + quad * 8, xoff, xrow);
    xpart(accB, bx, xb + (size_t)(m0B + lr) * xrow + w * 128 + quad * 8, xoff, xrow);

    for (int t = 0; t < Tn; ++t) {
        const size_t hbase = (size_t)t * (Bn * Hn);
        const size_t obase = (size_t)(t + 1) * (Bn * Hn);

        // ================= chain A half =================
        if (t > 0) {                                    // h_all[t] rows m0A ready?
            unsigned int* pf = flA + w * 8 + (lane & 7);
            while (true) {
                unsigned int v = __hip_atomic_load(pf, __ATOMIC_RELAXED,
                                                   __HIP_MEMORY_SCOPE_AGENT);
                if (__all((int)(v >= (unsigned int)t))) break;
                __builtin_amdgcn_s_sleep(1);
            }
            asm volatile("" ::: "memory");
        }
        hpart(accA, bh, h_all + hbase + (size_t)(m0A + lr) * Hn + w * 256 + quad * 8, hoff);

        // reduce write A (C/D layout row=quad*4+reg, col=lane&15)
        #pragma unroll
        for (int mi = 0; mi < 2; ++mi)
            #pragma unroll
            for (int ni = 0; ni < 2; ++ni)
                #pragma unroll
                for (int rr = 0; rr < 4; ++rr)
                    redA[w][mi * 16 + quad * 4 + rr][ni * 16 + lr] = accA[mi][ni][rr];
        __builtin_amdgcn_sched_barrier(0);
        asm volatile("s_waitcnt lgkmcnt(0)" ::: "memory");
        __builtin_amdgcn_s_barrier();                   // sync1a (LDS only)
        __builtin_amdgcn_sched_barrier(0);
        {   // final reduce A + tanh + store (4 B = 2 bf16 per thread)
            int j = threadIdx.x << 1;
            int row = j >> 5;                           // 0..31
            int c0 = j & 31;                            // even
            float2 s0 = *(const float2*)&redA[0][row][c0];
            float2 s1 = *(const float2*)&redA[1][row][c0];
            float2 s2 = *(const float2*)&redA[2][row][c0];
            float2 s3 = *(const float2*)&redA[3][row][c0];
            float2 s4 = *(const float2*)&redA[4][row][c0];
            float2 s5 = *(const float2*)&redA[5][row][c0];
            float2 s6 = *(const float2*)&redA[6][row][c0];
            float2 s7 = *(const float2*)&redA[7][row][c0];
            float sx = ((s0.x + s1.x) + (s2.x + s3.x)) + ((s4.x + s5.x) + (s6.x + s7.x));
            float sy = ((s0.y + s1.y) + (s2.y + s3.y)) + ((s4.y + s5.y) + (s6.y + s7.y));
            unsigned int o = (unsigned int)f2bf(fast_tanh(sx))
                           | ((unsigned int)f2bf(fast_tanh(sy)) << 16);
            unsigned int* dst = (unsigned int*)
                (h_all + obase + (size_t)(m0A + row) * Hn + n0 + c0);
            __hip_atomic_store(dst, o, __ATOMIC_RELAXED, __HIP_MEMORY_SCOPE_AGENT);
        }
        __syncthreads();                                // sync2a: vmcnt(0), A-store drained
        if (t < Tn - 1) {
            if (threadIdx.x == 0)
                __hip_atomic_store(bar + fA, (unsigned int)(t + 1), __ATOMIC_RELAXED,
                                   __HIP_MEMORY_SCOPE_AGENT);
            zero_acc(accA);                             // x-part A(t+1): off-chain
            xpart(accA, bx, xb + (size_t)(t + 1) * In + (size_t)(m0A + lr) * xrow
                            + w * 128 + quad * 8, xoff, xrow);
        }

        // ================= chain B half =================
        if (t > 0) {                                    // h_all[t] rows m0B ready?
            unsigned int* pf = flB + w * 8 + (lane & 7);
            while (true) {
                unsigned int v = __hip_atomic_load(pf, __ATOMIC_RELAXED,
                                                   __HIP_MEMORY_SCOPE_AGENT);
                if (__all((int)(v >= (unsigned int)t))) break;
                __builtin_amdgcn_s_sleep(1);
            }
            asm volatile("" ::: "memory");
        }
        hpart(accB, bh, h_all + hbase + (size_t)(m0B + lr) * Hn + w * 256 + quad * 8, hoff);

        #pragma unroll
        for (int mi = 0; mi < 2; ++mi)
            #pragma unroll
            for (int ni = 0; ni < 2; ++ni)
                #pragma unroll
                for (int rr = 0; rr < 4; ++rr)
                    redB[w][mi * 16 + quad * 4 + rr][ni * 16 + lr] = accB[mi][ni][rr];
        __builtin_amdgcn_sched_barrier(0);
        asm volatile("s_waitcnt lgkmcnt(0)" ::: "memory");
        __builtin_amdgcn_s_barrier();                   // sync1b (LDS only)
        __builtin_amdgcn_sched_barrier(0);
        {   // final reduce B + tanh + store
            int j = threadIdx.x << 1;
            int row = j >> 5;
            int c0 = j & 31;
            float2 s0 = *(const float2*)&redB[0][row][c0];
            float2 s1 = *(const float2*)&redB[1][row][c0];
            float2 s2 = *(const float2*)&redB[2][row][c0];
            float2 s3 = *(const float2*)&redB[3][row][c0];
            float2 s4 = *(const float2*)&redB[4][row][c0];
            float2 s5 = *(const float2*)&redB[5][row][c0];
            float2 s6 = *(const float2*)&redB[6][row][c0];
            float2 s7 = *(const float2*)&redB[7][row][c0];
            float sx = ((s0.x + s1.x) + (s2.x + s3.x)) + ((s4.x + s5.x) + (s6.x + s7.x));
            float sy = ((s0.y + s1.y) + (s2.y + s3.y)) + ((s4.y + s5.y) + (s6.y + s7.y));
            unsigned int o = (unsigned int)f2bf(fast_tanh(sx))
                           | ((unsigned int)f2bf(fast_tanh(sy)) << 16);
            unsigned int* dst = (unsigned int*)
                (h_all + obase + (size_t)(m0B + row) * Hn + n0 + c0);
            __hip_atomic_store(dst, o, __ATOMIC_RELAXED, __HIP_MEMORY_SCOPE_AGENT);
        }
        __syncthreads();                                // sync2b: vmcnt(0), B-store drained
        if (t < Tn - 1) {
            if (threadIdx.x == 0)
                __hip_atomic_store(bar + fB, (unsigned int)(t + 1), __ATOMIC_RELAXED,
                                   __HIP_MEMORY_SCOPE_AGENT);
            zero_acc(accB);                             // x-part B(t+1): off-chain
            xpart(accB, bx, xb + (size_t)(t + 1) * In + (size_t)(m0B + lr) * xrow
                            + w * 128 + quad * 8, xoff, xrow);
        }
    }
}

// ---- output projection ---------------------------------------------------
// y[b][t][o] = h_all[t+1][b][:] . lin_w[o][:] + lin_b[o]. One 16-row wave per 16 (t,b) rows.
__global__ __launch_bounds__(256)
void gemm2_kernel(const unsigned short* __restrict__ h_all, const unsigned short* __restrict__ lwb,
                  const float* __restrict__ lb, float* __restrict__ y) {
    int gw = blockIdx.x * 4 + (threadIdx.x >> 6);       // 0..1599
    int lane = threadIdx.x & 63, quad = lane >> 4, lr = lane & 15;
    int m0 = gw * 16;
    int t = m0 >> 8;
    int b0 = m0 & 255;
    const unsigned short* ah = h_all + ((size_t)(t + 1) * Bn + b0 + lr) * Hn + quad * 8;
    const unsigned short* bh = lwb + (size_t)lr * Hn + quad * 8;
    f32x4 acc0 = {0.f, 0.f, 0.f, 0.f}, acc1 = {0.f, 0.f, 0.f, 0.f};
    #pragma unroll
    for (int k0 = 0; k0 < Hn; k0 += 64) {
        s8v a0 = *(const s8v*)(ah + k0);
        s8v b0 = *(const s8v*)(bh + k0);
        acc0 = __builtin_amdgcn_mfma_f32_16x16x32_bf16(a0, b0, acc0, 0, 0, 0);
        s8v a1 = *(const s8v*)(ah + k0 + 32);
        s8v b1 = *(const s8v*)(bh + k0 + 32);
        acc1 = __builtin_amdgcn_mfma_f32_16x16x32_bf16(a1, b1, acc1, 0, 0, 0);
    }
    acc0 = acc0 + acc1;
    if (lr < On) {
        float bias = lb[lr];
        #pragma unroll
        for (int rr = 0; rr < 4; ++rr) {
            int b = b0 + quad * 4 + rr;
            y[(size_t)b * (Tn * On) + t * On + lr] = acc0[rr] + bias;
        }
    }
}

// ---- host ----------------------------------------------------------------

extern "C" void kernel_launch(void* const* d_in, const int* in_sizes, int n_in,
                              void* d_out, int out_size, void* d_ws, size_t ws_size,
                              hipStream_t stream) {
    const float* x   = (const float*)d_in[0];
    const float* h0  = (const float*)d_in[1];
    const float* Win = (const float*)d_in[2];
    const float* W   = (const float*)d_in[3];
    const float* lw  = (const float*)d_in[4];
    const float* lb  = (const float*)d_in[5];
    float* y = (float*)d_out;

    // ws layout (bf16 elems): ~171 MB total
    unsigned short* ws    = (unsigned short*)d_ws;
    unsigned short* xb    = ws;                                  // 26,214,400 elems
    unsigned short* BTm   = xb + (size_t)Bn * Tn * In;           //  6,291,456 elems [2048][3072]
    unsigned short* h_all = BTm + (size_t)Hn * Kc;               // 52,953,088 elems [(T+1)][B][H]
    unsigned short* lwb   = h_all + (size_t)(Tn + 1) * Bn * Hn;  //     32,768 elems [16][2048]
    unsigned int*   bar   = (unsigned int*)(lwb + 32768);        // 512 uints flag block

    conv_x_kernel<<<25600, 256, 0, stream>>>((const float4*)x, (ushort4*)xb);
    transpose_bf16_kernel<<<dim3(32, 64), 256, 0, stream>>>(Win, BTm, Hn, Kc, 0);
    transpose_bf16_kernel<<<dim3(64, 64), 256, 0, stream>>>(W, BTm, Hn, Kc, In);
    small_conv_kernel<<<2176, 256, 0, stream>>>(h0, lw, h_all, lwb, bar);

    scan_kernel<<<256, 512, 0, stream>>>(xb, BTm, h_all, bar);

    gemm2_kernel<<<400, 256, 0, stream>>>(h_all, lwb, lb, y);
}